// Round 14
// baseline (120.317 us; speedup 1.0000x reference)
//
#include <hip/hip_runtime.h>
#include <math.h>
#include <stdint.h>

#define NG 8
#define GS 2048
#define DM 512
#define NE 64
#define CAP 32
#define NROWS (NG * GS)                       // 16384 total rows (g,s)
#define COMBINE_ELEMS (33554432ull)           // 8*2048*64*32

#define N4 16777216                           // 268435456 B / 16
#define GATE_BLOCKS 512                       // 32 rows per block, 2 waves
#define XST 516                               // staged x row stride (words)
#define TBS 21                                // transpose buffer stride (odd)

typedef float f32x4 __attribute__((ext_vector_type(4)));
typedef double f64x2 __attribute__((ext_vector_type(2)));
typedef double f64x4 __attribute__((ext_vector_type(4)));
typedef unsigned long long u64;

// ---------------------------------------------------------------------------
// JAX Threefry-2x32 (partitionable path).  [verified: rounds 1,3-5,7-13]
// ---------------------------------------------------------------------------
__device__ __forceinline__ void threefry2x32(uint32_t k0, uint32_t k1,
                                             uint32_t x0, uint32_t x1,
                                             uint32_t& o0, uint32_t& o1) {
  uint32_t ks[3] = {k0, k1, k0 ^ k1 ^ 0x1BD11BDAu};
  x0 += ks[0];
  x1 += ks[1];
  const uint32_t rot[2][4] = {{13u, 15u, 26u, 6u}, {17u, 29u, 16u, 24u}};
#pragma unroll
  for (int i = 0; i < 5; ++i) {
#pragma unroll
    for (int j = 0; j < 4; ++j) {
      uint32_t r = rot[i & 1][j];
      x0 += x1;
      x1 = (x1 << r) | (x1 >> (32u - r));
      x1 ^= x0;
    }
    x0 += ks[(i + 1) % 3];
    x1 += ks[(i + 2) % 3] + (uint32_t)(i + 1);
  }
  o0 = x0;
  o1 = x1;
}

// XLA ErfInv (f32), Giles polynomial — constants bit-match xla math.cc.
__device__ __forceinline__ float erfinv_xla(float x) {
  float w = -log1pf(-x * x);
  float p;
  if (w < 5.0f) {
    w = w - 2.5f;
    p = 2.81022636e-08f;
    p = __fmaf_rn(p, w, 3.43273939e-07f);
    p = __fmaf_rn(p, w, -3.5233877e-06f);
    p = __fmaf_rn(p, w, -4.39150654e-06f);
    p = __fmaf_rn(p, w, 0.00021858087f);
    p = __fmaf_rn(p, w, -0.00125372503f);
    p = __fmaf_rn(p, w, -0.00417768164f);
    p = __fmaf_rn(p, w, 0.246640727f);
    p = __fmaf_rn(p, w, 1.50140941f);
  } else {
    w = sqrtf(w) - 3.0f;
    p = -0.000200214257f;
    p = __fmaf_rn(p, w, 0.000100950558f);
    p = __fmaf_rn(p, w, 0.00134934322f);
    p = __fmaf_rn(p, w, -0.00367342844f);
    p = __fmaf_rn(p, w, 0.00573950773f);
    p = __fmaf_rn(p, w, -0.0076224613f);
    p = __fmaf_rn(p, w, 0.00943887047f);
    p = __fmaf_rn(p, w, 1.00167406f);
    p = __fmaf_rn(p, w, 2.83297682f);
  }
  return p * x;
}

__device__ __forceinline__ float jax_normal(uint32_t idx) {
  uint32_t o0, o1;
  threefry2x32(0u, 42u, 0u, idx, o0, o1);
  uint32_t bits = o0 ^ o1;
  float f = __uint_as_float((bits >> 9) | 0x3f800000u) - 1.0f;  // [0,1)
  const float lo = __uint_as_float(0xBF7FFFFFu);                // -0.99999994
  float v = fmaxf(lo, f * 2.0f + lo);
  return __uint_as_float(0x3FB504F3u) * erfinv_xla(v);  // sqrt(2)_f32 * erfinv
}

// ---------------------------------------------------------------------------
// Kernel P: reformat W -> f64, layout Wd[row=kk*4+k4][i15][t] so the gate's
// per-kk B-operands are two coalesced f64x2 loads with no cvt in the loop
// (round-13 lesson: the scalar-gather W load + cvt chain, exposed at 1
// wave/SIMD, held gate at ~60 us vs its 13.7 us MFMA floor).
// Same f32->f64 exact conversion -> bit-identical gates.
// ---------------------------------------------------------------------------
__global__ __launch_bounds__(256) void wprep_kernel(
    const float* __restrict__ Wt, double* __restrict__ Wd) {
  const int i = blockIdx.x * 256 + threadIdx.x;   // 0..32767
  const int t = i & 3, i15 = (i >> 2) & 15, row = i >> 6;
  Wd[i] = (double)Wt[row * NE + t * 16 + i15];
}

// ---------------------------------------------------------------------------
// Kernel 0: zero the 256 MB output (plain f32x4, exact partition) — ~45 us,
// near the HBM write floor.  [measured round 12]
// ---------------------------------------------------------------------------
__global__ __launch_bounds__(256) void zero_kernel(f32x4* __restrict__ p) {
  const int b = blockIdx.x * 1024 + threadIdx.x;  // f32x4 units
  const f32x4 z = {0.f, 0.f, 0.f, 0.f};
#pragma unroll
  for (int j = 0; j < 4; ++j) p[b + j * 256] = z;
}

// ---------------------------------------------------------------------------
// Kernel 1: gate. ROUND-14 CHANGE: B-operands from prepped Wd via two
// coalesced f64x2 loads per kk, software-prefetched one kk ahead so the
// 256-cyc MFMA block always hides the load. Accumulation order unchanged
// (t=0..3 then kk) -> bit-identical gates [absmax 4.8828e-4, 7 rounds].
// ---------------------------------------------------------------------------
__global__ __launch_bounds__(128) void gate_kernel(
    const float* __restrict__ x,    // (NROWS, 512)
    const double* __restrict__ Wd,  // (512, 16, 4) prepped
    float* __restrict__ gatesT) {   // (NG*NE, GS)
  __shared__ float xs[32 * XST];    // 66048 B -> 2 blocks/CU
  const int gid = blockIdx.x;         // 0..511
  const int tid = threadIdx.x;
  const int l = tid & 63;             // lane
  const int w = tid >> 6;             // wave 0..1
  const int row0b = gid * 32;         // block's first row
  const int row0 = row0b + w * 16;    // wave's first row

  const int i15 = l & 15;             // A row / B-C col position
  const int k4 = l >> 4;              // k-slot within K=4

  // --- runtime probe: which x-row does acc[*][r] hold?  [verified r7-r13]
  f64x4 dr = {0., 0., 0., 0.};
  dr = __builtin_amdgcn_mfma_f64_16x16x4f64((double)i15, 0.25, dr, 0, 0, 0);
  int perm[4];
#pragma unroll
  for (int r = 0; r < 4; ++r) perm[r] = ((int)(dr[r] + 0.5)) & 15;

  // stage the whole 32x512 tile (single barrier, fully pipelined)
#pragma unroll 8
  for (int i = tid; i < 4096; i += 128) {
    const int r = i >> 7, c = (i & 127) << 2;
    *(f32x4*)&xs[r * XST + c] =
        *(const f32x4*)&x[(size_t)(row0b + r) * DM + c];
  }
  __syncthreads();

  // K-loop: 128 steps of K=4, order identical to rounds 9-13.
  f64x4 acc[4] = {{0., 0., 0., 0.}, {0., 0., 0., 0.},
                  {0., 0., 0., 0.}, {0., 0., 0., 0.}};
  const float* xrow = &xs[(w * 16 + i15) * XST + k4];
  const double* wl = Wd + k4 * 64 + i15 * 4;   // + kk*256 per step
  f64x2 b01 = *(const f64x2*)(wl + 0);
  f64x2 b23 = *(const f64x2*)(wl + 2);
#pragma unroll 4
  for (int kk = 0; kk < 128; ++kk) {
    const int nk = (kk + 1) & 127;             // last prefetch wraps (unused)
    const f64x2 nb01 = *(const f64x2*)(wl + nk * 256 + 0);
    const f64x2 nb23 = *(const f64x2*)(wl + nk * 256 + 2);
    const double a = (double)xrow[kk * 4];
    acc[0] = __builtin_amdgcn_mfma_f64_16x16x4f64(a, b01[0], acc[0], 0, 0, 0);
    acc[1] = __builtin_amdgcn_mfma_f64_16x16x4f64(a, b01[1], acc[1], 0, 0, 0);
    acc[2] = __builtin_amdgcn_mfma_f64_16x16x4f64(a, b23[0], acc[2], 0, 0, 0);
    acc[3] = __builtin_amdgcn_mfma_f64_16x16x4f64(a, b23[1], acc[3], 0, 0, 0);
    b01 = nb01;
    b23 = nb23;
  }

  // noise + fp64 softmax. acc[t][r] = logits[row0+perm[r]][e=16t+i15].
  float gatef[4][4];  // [t][r]
#pragma unroll
  for (int r = 0; r < 4; ++r) {
    const int row = row0 + perm[r];
    double v[4];
    double m = -1.0e300;
#pragma unroll
    for (int t = 0; t < 4; ++t) {
      const float logit = (float)acc[t][r];
      const float noised =
          logit + 0.015625f * jax_normal((uint32_t)(row * NE + 16 * t + i15));
      v[t] = (double)noised;
      m = fmax(m, v[t]);
    }
#pragma unroll
    for (int off = 1; off < 16; off <<= 1) m = fmax(m, __shfl_xor(m, off, 64));
    double s = 0.0;
#pragma unroll
    for (int t = 0; t < 4; ++t) {
      v[t] = exp(v[t] - m);
      s += v[t];
    }
#pragma unroll
    for (int off = 1; off < 16; off <<= 1) s += __shfl_xor(s, off, 64);
#pragma unroll
    for (int t = 0; t < 4; ++t) gatef[t][r] = (float)(v[t] / s);
  }

  // per-wave LDS transpose into this wave's own (dead) x-slice; no barrier.
  float* tb = xs + w * (NE * TBS);
#pragma unroll
  for (int t = 0; t < 4; ++t)
#pragma unroll
    for (int r = 0; r < 4; ++r)
      tb[(16 * t + i15) * TBS + perm[r]] = gatef[t][r];

  const int g = row0 >> 11;           // group
  const int s0 = row0 & (GS - 1);     // first s of this wave's 16
  float* drow = gatesT + ((size_t)(g * NE + l)) * GS + s0;  // lane l -> expert l
#pragma unroll
  for (int c = 0; c < 4; ++c) {
    f32x4 o;
#pragma unroll
    for (int i = 0; i < 4; ++i) o[i] = tb[l * TBS + 4 * c + i];
    *(f32x4*)&drow[4 * c] = o;
  }
}

// ---------------------------------------------------------------------------
// Kernel 2: topk — bitonic merge-prune, one wave per (g,e).  [verified r13;
// keys (vbits<<32)|(2047-s): exact lax.top_k value/tie semantics]
// ---------------------------------------------------------------------------
__global__ __launch_bounds__(64) void topk_kernel(
    const float* __restrict__ gatesT,  // (NG*NE, GS)
    float* __restrict__ out) {         // combine ++ dispatch
  const int ge = blockIdx.x;  // == g*64 + e
  const int g = ge >> 6;
  const int e = ge & 63;
  const int lane = threadIdx.x;

  const float* base = gatesT + (size_t)ge * GS;
  u64 K[32];
#pragma unroll
  for (int k = 0; k < 8; ++k) {
    const f32x4 t = *(const f32x4*)(base + k * 256 + lane * 4);
#pragma unroll
    for (int i = 0; i < 4; ++i) {
      const int s = k * 256 + lane * 4 + i;
      K[k * 4 + i] = ((u64)__float_as_uint(t[i]) << 32) | (u64)(2047 - s);
    }
  }

  // ---- per-lane bitonic sort of 32 keys, ascending ----
#pragma unroll
  for (int k = 2; k <= 32; k <<= 1) {
#pragma unroll
    for (int d = k >> 1; d > 0; d >>= 1) {
#pragma unroll
      for (int j = 0; j < 32; ++j) {
        const int ixj = j ^ d;
        if (ixj > j) {
          const bool asc = ((j & k) == 0);
          const u64 a = K[j], b = K[ixj];
          const bool sw = asc ? (a > b) : (a < b);
          K[j] = sw ? b : a;
          K[ixj] = sw ? a : b;
        }
      }
    }
  }

  // ---- 6 butterfly merge-prune levels ----
#pragma unroll
  for (int m = 1; m < 64; m <<= 1) {
    u64 tmp[32];
#pragma unroll
    for (int j = 0; j < 32; ++j) tmp[j] = __shfl_xor(K[31 - j], m, 64);
#pragma unroll
    for (int j = 0; j < 32; ++j) K[j] = (K[j] > tmp[j]) ? K[j] : tmp[j];
#pragma unroll
    for (int d = 16; d > 0; d >>= 1) {
#pragma unroll
      for (int j = 0; j < 32; ++j) {
        if ((j & d) == 0) {
          const u64 a = K[j], b = K[j | d];
          const bool sw = (a > b);
          K[j] = sw ? b : a;
          K[j | d] = sw ? a : b;
        }
      }
    }
  }

  // ---- emit: c-th pick = K[31-c]; all lanes hold identical lists ----
  float* combine = out;                   // (G,S,E,C)
  float* dispatch = out + COMBINE_ELEMS;  // (G,E,C,S)
#pragma unroll
  for (int c = 0; c < CAP; ++c) {
    if (lane == c) {
      const u64 key = K[31 - c];
      const float v = __uint_as_float((uint32_t)(key >> 32));
      const int s = 2047 - (int)(key & 0x7FFull);
      combine[(((size_t)(g * GS + s)) * NE + e) * CAP + c] = v;
      dispatch[(((size_t)(g * NE + e)) * CAP + c) * GS + s] = 1.0f;
    }
  }
}

extern "C" void kernel_launch(void* const* d_in, const int* in_sizes, int n_in,
                              void* d_out, int out_size, void* d_ws,
                              size_t ws_size, hipStream_t stream) {
  (void)in_sizes; (void)n_in; (void)ws_size; (void)out_size;
  const float* x = (const float*)d_in[0];   // (8,2048,512) f32
  const float* Wt = (const float*)d_in[1];  // (512,64) f32
  float* out = (float*)d_out;
  float* gatesT = (float*)d_ws;                       // 4 MB
  double* Wd = (double*)((char*)d_ws + ((size_t)NROWS * NE * 4));  // 256 KB

  wprep_kernel<<<128, 256, 0, stream>>>(Wt, Wd);
  zero_kernel<<<N4 / 1024, 256, 0, stream>>>((f32x4*)out);
  gate_kernel<<<GATE_BLOCKS, 128, 0, stream>>>(x, Wd, gatesT);
  topk_kernel<<<NG * NE, 64, 0, stream>>>(gatesT, out);
}

// Round 15
// 119.441 us; speedup vs baseline: 1.0073x; 1.0073x over previous
//
#include <hip/hip_runtime.h>
#include <math.h>
#include <stdint.h>

#define NG 8
#define GS 2048
#define DM 512
#define NE 64
#define CAP 32
#define NROWS (NG * GS)                       // 16384 total rows (g,s)
#define COMBINE_ELEMS (33554432ull)           // 8*2048*64*32

#define GATE_BLOCKS 512                       // 32 rows per block, 2 waves
#define XST 516                               // staged x row stride (words)
#define TBS 21                                // transpose buffer stride (odd)

typedef float f32x4 __attribute__((ext_vector_type(4)));
typedef double f64x2 __attribute__((ext_vector_type(2)));
typedef double f64x4 __attribute__((ext_vector_type(4)));
typedef unsigned long long u64;

// ---------------------------------------------------------------------------
// JAX Threefry-2x32 (partitionable path).  [verified: rounds 1,3-5,7-14]
// ---------------------------------------------------------------------------
__device__ __forceinline__ void threefry2x32(uint32_t k0, uint32_t k1,
                                             uint32_t x0, uint32_t x1,
                                             uint32_t& o0, uint32_t& o1) {
  uint32_t ks[3] = {k0, k1, k0 ^ k1 ^ 0x1BD11BDAu};
  x0 += ks[0];
  x1 += ks[1];
  const uint32_t rot[2][4] = {{13u, 15u, 26u, 6u}, {17u, 29u, 16u, 24u}};
#pragma unroll
  for (int i = 0; i < 5; ++i) {
#pragma unroll
    for (int j = 0; j < 4; ++j) {
      uint32_t r = rot[i & 1][j];
      x0 += x1;
      x1 = (x1 << r) | (x1 >> (32u - r));
      x1 ^= x0;
    }
    x0 += ks[(i + 1) % 3];
    x1 += ks[(i + 2) % 3] + (uint32_t)(i + 1);
  }
  o0 = x0;
  o1 = x1;
}

// XLA ErfInv (f32), Giles polynomial — constants bit-match xla math.cc.
__device__ __forceinline__ float erfinv_xla(float x) {
  float w = -log1pf(-x * x);
  float p;
  if (w < 5.0f) {
    w = w - 2.5f;
    p = 2.81022636e-08f;
    p = __fmaf_rn(p, w, 3.43273939e-07f);
    p = __fmaf_rn(p, w, -3.5233877e-06f);
    p = __fmaf_rn(p, w, -4.39150654e-06f);
    p = __fmaf_rn(p, w, 0.00021858087f);
    p = __fmaf_rn(p, w, -0.00125372503f);
    p = __fmaf_rn(p, w, -0.00417768164f);
    p = __fmaf_rn(p, w, 0.246640727f);
    p = __fmaf_rn(p, w, 1.50140941f);
  } else {
    w = sqrtf(w) - 3.0f;
    p = -0.000200214257f;
    p = __fmaf_rn(p, w, 0.000100950558f);
    p = __fmaf_rn(p, w, 0.00134934322f);
    p = __fmaf_rn(p, w, -0.00367342844f);
    p = __fmaf_rn(p, w, 0.00573950773f);
    p = __fmaf_rn(p, w, -0.0076224613f);
    p = __fmaf_rn(p, w, 0.00943887047f);
    p = __fmaf_rn(p, w, 1.00167406f);
    p = __fmaf_rn(p, w, 2.83297682f);
  }
  return p * x;
}

__device__ __forceinline__ float jax_normal(uint32_t idx) {
  uint32_t o0, o1;
  threefry2x32(0u, 42u, 0u, idx, o0, o1);
  uint32_t bits = o0 ^ o1;
  float f = __uint_as_float((bits >> 9) | 0x3f800000u) - 1.0f;  // [0,1)
  const float lo = __uint_as_float(0xBF7FFFFFu);                // -0.99999994
  float v = fmaxf(lo, f * 2.0f + lo);
  return __uint_as_float(0x3FB504F3u) * erfinv_xla(v);  // sqrt(2)_f32 * erfinv
}

// ---------------------------------------------------------------------------
// Kernel P: reformat W -> f64 [r14; kept for gate bit-stability].
// ---------------------------------------------------------------------------
__global__ __launch_bounds__(256) void wprep_kernel(
    const float* __restrict__ Wt, double* __restrict__ Wd) {
  const int i = blockIdx.x * 256 + threadIdx.x;   // 0..32767
  const int t = i & 3, i15 = (i >> 2) & 15, row = i >> 6;
  Wd[i] = (double)Wt[row * NE + t * 16 + i15];
}

// ---------------------------------------------------------------------------
// Kernel 1: gate — BYTE-IDENTICAL to round 14 (absmax 4.8828e-4, 8 rounds).
// ---------------------------------------------------------------------------
__global__ __launch_bounds__(128) void gate_kernel(
    const float* __restrict__ x,    // (NROWS, 512)
    const double* __restrict__ Wd,  // (512, 16, 4) prepped
    float* __restrict__ gatesT) {   // (NG*NE, GS)
  __shared__ float xs[32 * XST];    // 66048 B -> 2 blocks/CU
  const int gid = blockIdx.x;         // 0..511
  const int tid = threadIdx.x;
  const int l = tid & 63;             // lane
  const int w = tid >> 6;             // wave 0..1
  const int row0b = gid * 32;         // block's first row
  const int row0 = row0b + w * 16;    // wave's first row

  const int i15 = l & 15;             // A row / B-C col position
  const int k4 = l >> 4;              // k-slot within K=4

  // --- runtime probe: which x-row does acc[*][r] hold?  [verified r7-r14]
  f64x4 dr = {0., 0., 0., 0.};
  dr = __builtin_amdgcn_mfma_f64_16x16x4f64((double)i15, 0.25, dr, 0, 0, 0);
  int perm[4];
#pragma unroll
  for (int r = 0; r < 4; ++r) perm[r] = ((int)(dr[r] + 0.5)) & 15;

  // stage the whole 32x512 tile (single barrier, fully pipelined)
#pragma unroll 8
  for (int i = tid; i < 4096; i += 128) {
    const int r = i >> 7, c = (i & 127) << 2;
    *(f32x4*)&xs[r * XST + c] =
        *(const f32x4*)&x[(size_t)(row0b + r) * DM + c];
  }
  __syncthreads();

  // K-loop: 128 steps of K=4, order identical to rounds 9-14.
  f64x4 acc[4] = {{0., 0., 0., 0.}, {0., 0., 0., 0.},
                  {0., 0., 0., 0.}, {0., 0., 0., 0.}};
  const float* xrow = &xs[(w * 16 + i15) * XST + k4];
  const double* wl = Wd + k4 * 64 + i15 * 4;   // + kk*256 per step
  f64x2 b01 = *(const f64x2*)(wl + 0);
  f64x2 b23 = *(const f64x2*)(wl + 2);
#pragma unroll 4
  for (int kk = 0; kk < 128; ++kk) {
    const int nk = (kk + 1) & 127;             // last prefetch wraps (unused)
    const f64x2 nb01 = *(const f64x2*)(wl + nk * 256 + 0);
    const f64x2 nb23 = *(const f64x2*)(wl + nk * 256 + 2);
    const double a = (double)xrow[kk * 4];
    acc[0] = __builtin_amdgcn_mfma_f64_16x16x4f64(a, b01[0], acc[0], 0, 0, 0);
    acc[1] = __builtin_amdgcn_mfma_f64_16x16x4f64(a, b01[1], acc[1], 0, 0, 0);
    acc[2] = __builtin_amdgcn_mfma_f64_16x16x4f64(a, b23[0], acc[2], 0, 0, 0);
    acc[3] = __builtin_amdgcn_mfma_f64_16x16x4f64(a, b23[1], acc[3], 0, 0, 0);
    b01 = nb01;
    b23 = nb23;
  }

  // noise + fp64 softmax. acc[t][r] = logits[row0+perm[r]][e=16t+i15].
  float gatef[4][4];  // [t][r]
#pragma unroll
  for (int r = 0; r < 4; ++r) {
    const int row = row0 + perm[r];
    double v[4];
    double m = -1.0e300;
#pragma unroll
    for (int t = 0; t < 4; ++t) {
      const float logit = (float)acc[t][r];
      const float noised =
          logit + 0.015625f * jax_normal((uint32_t)(row * NE + 16 * t + i15));
      v[t] = (double)noised;
      m = fmax(m, v[t]);
    }
#pragma unroll
    for (int off = 1; off < 16; off <<= 1) m = fmax(m, __shfl_xor(m, off, 64));
    double s = 0.0;
#pragma unroll
    for (int t = 0; t < 4; ++t) {
      v[t] = exp(v[t] - m);
      s += v[t];
    }
#pragma unroll
    for (int off = 1; off < 16; off <<= 1) s += __shfl_xor(s, off, 64);
#pragma unroll
    for (int t = 0; t < 4; ++t) gatef[t][r] = (float)(v[t] / s);
  }

  // per-wave LDS transpose into this wave's own (dead) x-slice; no barrier.
  float* tb = xs + w * (NE * TBS);
#pragma unroll
  for (int t = 0; t < 4; ++t)
#pragma unroll
    for (int r = 0; r < 4; ++r)
      tb[(16 * t + i15) * TBS + perm[r]] = gatef[t][r];

  const int g = row0 >> 11;           // group
  const int s0 = row0 & (GS - 1);     // first s of this wave's 16
  float* drow = gatesT + ((size_t)(g * NE + l)) * GS + s0;  // lane l -> expert l
#pragma unroll
  for (int c = 0; c < 4; ++c) {
    f32x4 o;
#pragma unroll
    for (int i = 0; i < 4; ++i) o[i] = tb[l * TBS + 4 * c + i];
    *(f32x4*)&drow[4 * c] = o;
  }
}

// ---------------------------------------------------------------------------
// Kernel 2: topsel — bitonic merge-prune top-32 per (g,e) [selection logic
// verified r13/r14], ROUND-15 CHANGE: emits only the 32 sorted u64 keys
// ((vbits<<32)|(2047-s)) to a 128 KB scratch table; no output writes.
// ---------------------------------------------------------------------------
__global__ __launch_bounds__(64) void topsel_kernel(
    const float* __restrict__ gatesT,  // (NG*NE, GS)
    u64* __restrict__ topsel) {        // (NG*NE, CAP)
  const int ge = blockIdx.x;  // == g*64 + e
  const int lane = threadIdx.x;

  const float* base = gatesT + (size_t)ge * GS;
  u64 K[32];
#pragma unroll
  for (int k = 0; k < 8; ++k) {
    const f32x4 t = *(const f32x4*)(base + k * 256 + lane * 4);
#pragma unroll
    for (int i = 0; i < 4; ++i) {
      const int s = k * 256 + lane * 4 + i;
      K[k * 4 + i] = ((u64)__float_as_uint(t[i]) << 32) | (u64)(2047 - s);
    }
  }

  // per-lane bitonic sort of 32 keys, ascending
#pragma unroll
  for (int k = 2; k <= 32; k <<= 1) {
#pragma unroll
    for (int d = k >> 1; d > 0; d >>= 1) {
#pragma unroll
      for (int j = 0; j < 32; ++j) {
        const int ixj = j ^ d;
        if (ixj > j) {
          const bool asc = ((j & k) == 0);
          const u64 a = K[j], b = K[ixj];
          const bool sw = asc ? (a > b) : (a < b);
          K[j] = sw ? b : a;
          K[ixj] = sw ? a : b;
        }
      }
    }
  }

  // 6 butterfly merge-prune levels
#pragma unroll
  for (int m = 1; m < 64; m <<= 1) {
    u64 tmp[32];
#pragma unroll
    for (int j = 0; j < 32; ++j) tmp[j] = __shfl_xor(K[31 - j], m, 64);
#pragma unroll
    for (int j = 0; j < 32; ++j) K[j] = (K[j] > tmp[j]) ? K[j] : tmp[j];
#pragma unroll
    for (int d = 16; d > 0; d >>= 1) {
#pragma unroll
      for (int j = 0; j < 32; ++j) {
        if ((j & d) == 0) {
          const u64 a = K[j], b = K[j | d];
          const bool sw = (a > b);
          K[j] = sw ? b : a;
          K[j | d] = sw ? a : b;
        }
      }
    }
  }

  // emit c-th pick = K[31-c] (static indices; lane c stores entry c)
#pragma unroll
  for (int c = 0; c < CAP; ++c) {
    if (lane == c) topsel[(size_t)ge * CAP + c] = K[31 - c];
  }
}

// ---------------------------------------------------------------------------
// Kernel 3: writer — ROUND-15 NEW. Replaces zero_kernel + scattered output
// writes: densely writes ALL 268 MB (zeros and values in one pass).
// 2048 blocks (all-resident, 32 waves/CU) x 256 thr; block (ge, q=quarter):
//   dispatch rows c in [8q,8q+8): one-hot 2048-rows, 1 KB/wave-instr coalesced
//   combine rows s in [512q,512q+512): 32-float rows via LDS c_of_s lookup,
//     8x128B-aligned segments per wave-instr.
// ---------------------------------------------------------------------------
__global__ __launch_bounds__(256) void writer_kernel(
    const u64* __restrict__ topsel,   // (NG*NE, CAP)
    float* __restrict__ out) {        // combine ++ dispatch
  __shared__ int sel_s[CAP];
  __shared__ float sel_v[CAP];
  __shared__ unsigned char c_of_s[GS];
  const int b = blockIdx.x;
  const int ge = b >> 2, q = b & 3;
  const int g = ge >> 6, e = ge & 63;
  const int tid = threadIdx.x;
  const int lane = tid & 63, w = tid >> 6;

  ((u64*)c_of_s)[tid] = ~0ull;  // 256 threads x 8 B = 2048 B
  if (tid < CAP) {
    const u64 key = topsel[(size_t)ge * CAP + tid];
    sel_s[tid] = 2047 - (int)(key & 0x7FFull);
    sel_v[tid] = __uint_as_float((uint32_t)(key >> 32));
  }
  __syncthreads();
  if (tid < CAP) c_of_s[sel_s[tid]] = (unsigned char)tid;
  __syncthreads();

  // ---- dispatch (G,E,C,S): rows c = 8q + 2w + {0,1} ----
  float* drow_base = out + COMBINE_ELEMS + (size_t)ge * CAP * GS;
#pragma unroll
  for (int rr = 0; rr < 2; ++rr) {
    const int c = 8 * q + 2 * w + rr;
    const int sc = sel_s[c];
    float* rowp = drow_base + (size_t)c * GS;
#pragma unroll
    for (int j = 0; j < 8; ++j) {
      const int pos = j * 256 + lane * 4;
      f32x4 v;
      v[0] = (sc == pos + 0) ? 1.0f : 0.0f;
      v[1] = (sc == pos + 1) ? 1.0f : 0.0f;
      v[2] = (sc == pos + 2) ? 1.0f : 0.0f;
      v[3] = (sc == pos + 3) ? 1.0f : 0.0f;
      *(f32x4*)&rowp[pos] = v;
    }
  }

  // ---- combine (G,S,E,C): rows s = 512q + 128w + 8*it + (lane>>3) ----
  const int pos = (lane & 7) * 4;   // float offset within the 32-float row
#pragma unroll
  for (int it = 0; it < 16; ++it) {
    const int s = 512 * q + 128 * w + 8 * it + (lane >> 3);
    const int c = c_of_s[s];        // 0..31 or 255
    const float val = (c != 255) ? sel_v[c & 31] : 0.0f;
    const int d = c - pos;
    f32x4 v;
    v[0] = (d == 0) ? val : 0.0f;
    v[1] = (d == 1) ? val : 0.0f;
    v[2] = (d == 2) ? val : 0.0f;
    v[3] = (d == 3) ? val : 0.0f;
    *(f32x4*)&out[(((size_t)(g * GS + s)) * NE + e) * CAP + pos] = v;
  }
}

extern "C" void kernel_launch(void* const* d_in, const int* in_sizes, int n_in,
                              void* d_out, int out_size, void* d_ws,
                              size_t ws_size, hipStream_t stream) {
  (void)in_sizes; (void)n_in; (void)ws_size; (void)out_size;
  const float* x = (const float*)d_in[0];   // (8,2048,512) f32
  const float* Wt = (const float*)d_in[1];  // (512,64) f32
  float* out = (float*)d_out;
  float* gatesT = (float*)d_ws;                                    // 4 MB
  double* Wd = (double*)((char*)d_ws + ((size_t)NROWS * NE * 4));  // 256 KB
  u64* topsel = (u64*)((char*)Wd + (size_t)DM * NE * 8);           // 128 KB

  wprep_kernel<<<128, 256, 0, stream>>>(Wt, Wd);
  gate_kernel<<<GATE_BLOCKS, 128, 0, stream>>>(x, Wd, gatesT);
  topsel_kernel<<<NG * NE, 64, 0, stream>>>(gatesT, topsel);
  writer_kernel<<<NG * NE * 4, 256, 0, stream>>>(topsel, out);
}